// Round 16
// baseline (153.838 us; speedup 1.0000x reference)
//
#include <hip/hip_runtime.h>
#include <math.h>

typedef __attribute__((ext_vector_type(8))) short short8;
typedef __attribute__((ext_vector_type(4))) float f32x4;
typedef __attribute__((ext_vector_type(4))) unsigned short us4;

constexpr int NSEG = 16;
constexpr int CC   = 768;
constexpr int PP   = 197;
constexpr int NH   = 12;
constexpr int HD   = 64;
constexpr int NT   = 512;
constexpr int MN   = NT * CC;
constexpr float LN_EPS = 1e-5f;

// pass-through copy geometry, float4 units (p>=1 rows of every token)
constexpr unsigned CPT  = 196 * CC / 4;          // 37632
constexpr unsigned ROW4 = CC / 4;                // 192
constexpr unsigned W4TOT = (unsigned)NT * CPT;   // 19267584

// copy slices per kernel (float4), 3 kernels
constexpr unsigned L1 = 7340032u;
constexpr unsigned L2 = 6291456u;
constexpr unsigned L3 = W4TOT - L1 - L2;         // 5636096
constexpr unsigned B2 = L1, B3 = L1 + L2;

__device__ inline unsigned short f2bf(float f) {
    unsigned u = __float_as_uint(f);
    u += 0x7fffu + ((u >> 16) & 1u);
    return (unsigned short)(u >> 16);
}
__device__ inline float bf2f(unsigned short v) {
    return __uint_as_float((unsigned)v << 16);
}
__device__ inline unsigned cidx(unsigned i) {
    unsigned t = i / CPT;                 // magic-mul div
    return i + t * ROW4 + ROW4;
}
// streaming copy: NT loads (x read-once), REGULAR stores (R14: nt stores left stale
// poison lines in L2 and failed post-timing validation)
__device__ inline void copy_strided(const float* __restrict__ xf, float* __restrict__ of,
                                    unsigned base, unsigned len,
                                    unsigned ct, unsigned nth) {
    const f32x4* __restrict__ x4 = (const f32x4*)xf;
    f32x4* __restrict__ o4 = (f32x4*)of;
    for (unsigned i = ct; i < len; i += nth) {
        unsigned a = cidx(base + i);
        f32x4 v = __builtin_nontemporal_load(x4 + a);
        o4[a] = v;
    }
}

// ---------------- 64x64 MFMA bf16 tile, 4 waves, fragments direct from global ----------------
__device__ inline void gemm_tile_qkv(const unsigned short* __restrict__ A,
                                     const unsigned short* __restrict__ Bt,   // [n][k]
                                     const float* __restrict__ bias,
                                     unsigned short* __restrict__ outb,
                                     int by, int bx) {
    int tid  = threadIdx.x;
    int lane = tid & 63, wv = tid >> 6;
    int wr = wv >> 1, wc = wv & 1;
    int l15 = lane & 15, lh = lane >> 4;
    int m0 = by * 64 + wr * 32;
    int n0 = bx * 64 + wc * 32;
    f32x4 acc[2][2] = {};
    const unsigned short* Ar0 = A  + (size_t)(m0 + l15) * CC + lh * 8;
    const unsigned short* Ar1 = Ar0 + 16 * CC;
    const unsigned short* Br0 = Bt + (size_t)(n0 + l15) * CC + lh * 8;
    const unsigned short* Br1 = Br0 + 16 * CC;
    #pragma unroll 4
    for (int k0 = 0; k0 < CC; k0 += 32) {
        short8 a0 = *(const short8*)(Ar0 + k0);
        short8 a1 = *(const short8*)(Ar1 + k0);
        short8 b0 = *(const short8*)(Br0 + k0);
        short8 b1 = *(const short8*)(Br1 + k0);
        acc[0][0] = __builtin_amdgcn_mfma_f32_16x16x32_bf16(a0, b0, acc[0][0], 0, 0, 0);
        acc[0][1] = __builtin_amdgcn_mfma_f32_16x16x32_bf16(a0, b1, acc[0][1], 0, 0, 0);
        acc[1][0] = __builtin_amdgcn_mfma_f32_16x16x32_bf16(a1, b0, acc[1][0], 0, 0, 0);
        acc[1][1] = __builtin_amdgcn_mfma_f32_16x16x32_bf16(a1, b1, acc[1][1], 0, 0, 0);
    }
    #pragma unroll
    for (int mf = 0; mf < 2; ++mf)
        #pragma unroll
        for (int nf = 0; nf < 2; ++nf)
            #pragma unroll
            for (int r = 0; r < 4; ++r) {
                int row = m0 + mf * 16 + lh * 4 + r;
                int col = n0 + nf * 16 + l15;
                outb[(size_t)row * CC + col] = f2bf(acc[mf][nf][r] + bias[col]);
            }
}

// ================= K1: CVT (288 x 8 tiles) | LN (512) | ALL 2048 copy =================
__global__ __launch_bounds__(256) void k1(const float* __restrict__ x, const float* __restrict__ w1,
        const float* __restrict__ g, const float* __restrict__ bln,
        const float* __restrict__ Wq, const float* __restrict__ Wk,
        const float* __restrict__ Wv, const float* __restrict__ Wo,
        float* __restrict__ s_shift, unsigned short* __restrict__ tln,
        unsigned short* __restrict__ wt, float* __restrict__ out) {
    __shared__ float smem[32 * 33];
    int bid = blockIdx.x, tid = threadIdx.x;
    if (bid < 288) {
        #pragma unroll
        for (int rep = 0; rep < 8; ++rep) {
            int idx = bid + rep * 288;          // 0..2303
            int mat = idx / 576, tile = idx % 576;
            int tr = tile / 24, tc = tile % 24;
            const float* W = mat == 0 ? Wq : mat == 1 ? Wk : mat == 2 ? Wv : Wo;
            int lr = tid >> 3, lc = (tid & 7) * 4;
            float4 v = *(const float4*)(W + (size_t)(tr * 32 + lr) * CC + tc * 32 + lc);
            smem[lr * 33 + lc + 0] = v.x; smem[lr * 33 + lc + 1] = v.y;
            smem[lr * 33 + lc + 2] = v.z; smem[lr * 33 + lc + 3] = v.w;
            __syncthreads();
            int ln_ = tid >> 3, kc = (tid & 7) * 4;
            us4 o;
            #pragma unroll
            for (int j = 0; j < 4; ++j) o[j] = f2bf(smem[(kc + j) * 33 + ln_]);
            *(us4*)(wt + (size_t)mat * CC * CC + (size_t)(tc * 32 + ln_) * CC + tr * 32 + kc) = o;
            __syncthreads();
        }
    } else if (bid < 288 + NT) {
        int r = bid - 288, seg = r & (NSEG - 1);
        float vals[3]; float local = 0.f;
        #pragma unroll
        for (int i = 0; i < 3; ++i) {
            int c = tid + i * 256;
            float v = x[(size_t)r * PP * CC + c];
            if (seg > 0) v += w1[c] * x[(size_t)(r - 1) * PP * CC + c];
            vals[i] = v; local += v;
        }
        smem[tid] = local; __syncthreads();
        for (int off = 128; off > 0; off >>= 1) {
            if (tid < off) smem[tid] += smem[tid + off];
            __syncthreads();
        }
        float mu = smem[0] * (1.0f / CC); __syncthreads();
        float lv = 0.f;
        #pragma unroll
        for (int i = 0; i < 3; ++i) { float d = vals[i] - mu; lv += d * d; }
        smem[tid] = lv; __syncthreads();
        for (int off = 128; off > 0; off >>= 1) {
            if (tid < off) smem[tid] += smem[tid + off];
            __syncthreads();
        }
        float rstd = rsqrtf(smem[0] * (1.0f / CC) + LN_EPS);
        #pragma unroll
        for (int i = 0; i < 3; ++i) {
            int c = tid + i * 256;
            s_shift[(size_t)r * CC + c] = vals[i];
            tln[(size_t)r * CC + c] = f2bf((vals[i] - mu) * rstd * g[c] + bln[c]);
        }
    }
    copy_strided(x, out, 0u, L1, (unsigned)bid * 256 + tid, 2048u * 256);
}

// ================= K2: QKV GEMM (288) | out[p=0] init (8) | copy (1760) =================
__global__ __launch_bounds__(256) void k2(const unsigned short* __restrict__ tln,
        const unsigned short* __restrict__ wt,
        const float* __restrict__ bq, const float* __restrict__ bk, const float* __restrict__ bv,
        const float* __restrict__ bo, const float* __restrict__ s_shift,
        unsigned short* __restrict__ qkvb,
        const float* __restrict__ x, float* __restrict__ out) {
    int bid = blockIdx.x, tid = threadIdx.x;
    if (bid < 288) {
        int z = bid / 96, rem = bid % 96;
        int by = rem / 12, bx = rem % 12;
        const float* bias = z == 0 ? bq : (z == 1 ? bk : bv);
        gemm_tile_qkv(tln, wt + (size_t)z * CC * CC, bias, qkvb + (size_t)z * MN, by, bx);
        return;   // GEMM blocks do no copy
    }
    if (bid < 296) {
        // init out[p=0] = s_shift + bo (float4), 8 blocks x 256 threads x 48 f4
        const f32x4* ss4 = (const f32x4*)s_shift;
        const f32x4* bo4 = (const f32x4*)bo;
        f32x4* o4 = (f32x4*)out;
        for (unsigned i = (unsigned)(bid - 288) * 256 + tid; i < (unsigned)NT * ROW4; i += 8u * 256) {
            unsigned r = i / ROW4, c4 = i % ROW4;
            o4[(size_t)r * (PP * CC / 4) + c4] = ss4[i] + bo4[c4];
        }
    }
    copy_strided(x, out, B2, L2, (unsigned)(bid - 288) * 256 + tid, 1760u * 256);
}

// ================= K3: attn + per-head partial O-proj via atomicAdd (384) | copy (1664) =================
__global__ __launch_bounds__(256) void k3(const unsigned short* __restrict__ qkvb,
        const unsigned short* __restrict__ wto,
        float* __restrict__ out, const float* __restrict__ x) {
    int bid = blockIdx.x, tid = threadIdx.x;
    if (bid < 384) {
        const unsigned short* qb = qkvb;
        const unsigned short* kb = qkvb + MN;
        const unsigned short* vb = qkvb + 2 * MN;
        int bb = bid / NH, h = bid % NH;
        __shared__ float qs[16][HD], ks[16][HD], vs[16][HD];
        __shared__ float sc[16][17];
        __shared__ float rsum[16];
        __shared__ unsigned short ctxl[16][72];   // bf16 ctx, row pad -> conflict-free b128
        for (int i = tid; i < 16 * HD; i += 256) {
            int t = i >> 6, d = i & 63;
            size_t gidx = (size_t)(bb * NSEG + t) * CC + h * HD + d;
            qs[t][d] = bf2f(qb[gidx]); ks[t][d] = bf2f(kb[gidx]); vs[t][d] = bf2f(vb[gidx]);
        }
        __syncthreads();
        {
            int t = tid >> 4, s = tid & 15;
            float acc = 0.f;
            #pragma unroll
            for (int d = 0; d < HD; ++d) acc += qs[t][d] * ks[s][d];
            sc[t][s] = acc * 0.125f;
        }
        __syncthreads();
        if (tid < 16) {
            float m = -1e30f;
            #pragma unroll
            for (int s = 0; s < 16; ++s) m = fmaxf(m, sc[tid][s]);
            float sum = 0.f;
            #pragma unroll
            for (int s = 0; s < 16; ++s) { float e = __expf(sc[tid][s] - m); sc[tid][s] = e; sum += e; }
            rsum[tid] = sum;
        }
        __syncthreads();
        for (int i = tid; i < 16 * HD; i += 256) {
            int t = i >> 6, d = i & 63;
            float acc = 0.f;
            #pragma unroll
            for (int s = 0; s < 16; ++s) acc += sc[t][s] * vs[s][d];
            ctxl[t][d] = f2bf(acc / rsum[t]);
        }
        __syncthreads();
        // partial O-proj: ctx_h (16x64) @ Wo[h*64:(h+1)*64, :] -> atomicAdd into out[p=0]
        int lane = tid & 63, w = tid >> 6;
        int l15 = lane & 15, lh = lane >> 4;
        for (int ti = w; ti < 48; ti += 4) {
            int n0 = ti * 16;
            f32x4 acc = {0.f, 0.f, 0.f, 0.f};
            #pragma unroll
            for (int k0 = 0; k0 < HD; k0 += 32) {
                short8 a = *(const short8*)&ctxl[l15][k0 + lh * 8];
                short8 b = *(const short8*)(wto + (size_t)(n0 + l15) * CC + h * HD + k0 + lh * 8);
                acc = __builtin_amdgcn_mfma_f32_16x16x32_bf16(a, b, acc, 0, 0, 0);
            }
            #pragma unroll
            for (int r = 0; r < 4; ++r) {
                int row = lh * 4 + r;
                atomicAdd(&out[(size_t)(bb * NSEG + row) * (size_t)(PP * CC) + n0 + l15], acc[r]);
            }
        }
        return;   // attn blocks do no copy
    }
    copy_strided(x, out, B3, L3, (unsigned)(bid - 384) * 256 + tid, 1664u * 256);
}

extern "C" void kernel_launch(void* const* d_in, const int* in_sizes, int n_in,
                              void* d_out, int out_size, void* d_ws, size_t ws_size,
                              hipStream_t stream) {
    const float* x    = (const float*)d_in[0];
    const float* w1   = (const float*)d_in[1];
    const float* ln_g = (const float*)d_in[2];
    const float* ln_b = (const float*)d_in[3];
    const float* Wq   = (const float*)d_in[4];
    const float* bq   = (const float*)d_in[5];
    const float* Wk   = (const float*)d_in[6];
    const float* bk   = (const float*)d_in[7];
    const float* Wv   = (const float*)d_in[8];
    const float* bv   = (const float*)d_in[9];
    const float* Wo   = (const float*)d_in[10];
    const float* bo   = (const float*)d_in[11];
    float* out = (float*)d_out;

    float* s_shift = (float*)d_ws;                            // MN f32
    unsigned short* tln  = (unsigned short*)(s_shift + MN);   // MN bf16
    unsigned short* qkvb = tln + MN;                          // 3*MN bf16
    unsigned short* wt   = qkvb + 3 * (size_t)MN;             // 4*CC*CC bf16

    k1<<<2048, 256, 0, stream>>>(x, w1, ln_g, ln_b, Wq, Wk, Wv, Wo, s_shift, tln, wt, out);
    k2<<<2048, 256, 0, stream>>>(tln, wt, bq, bk, bv, bo, s_shift, qkvb, x, out);
    k3<<<2048, 256, 0, stream>>>(qkvb, wt + (size_t)3 * CC * CC, out, x);
}

// Round 17
// 141.564 us; speedup vs baseline: 1.0867x; 1.0867x over previous
//
#include <hip/hip_runtime.h>
#include <math.h>

typedef __attribute__((ext_vector_type(8))) short short8;
typedef __attribute__((ext_vector_type(4))) float f32x4;
typedef __attribute__((ext_vector_type(4))) unsigned short us4;

constexpr int NSEG = 16;
constexpr int CC   = 768;
constexpr int PP   = 197;
constexpr int NH   = 12;
constexpr int HD   = 64;
constexpr int NT   = 512;
constexpr int MN   = NT * CC;
constexpr float LN_EPS = 1e-5f;

// pass-through copy geometry, float4 units (p>=1 rows of every token)
constexpr unsigned CPT  = 196 * CC / 4;          // 37632
constexpr unsigned ROW4 = CC / 4;                // 192
constexpr unsigned W4TOT = (unsigned)NT * CPT;   // 19267584

// copy slices per kernel (float4)
constexpr unsigned L1 = 7077888u;
constexpr unsigned L2 = 5406720u;
constexpr unsigned L3 = 4423680u;
constexpr unsigned L4 = W4TOT - L1 - L2 - L3;    // 2359296
constexpr unsigned B2 = L1, B3 = L1 + L2, B4 = L1 + L2 + L3;

__device__ inline unsigned short f2bf(float f) {
    unsigned u = __float_as_uint(f);
    u += 0x7fffu + ((u >> 16) & 1u);
    return (unsigned short)(u >> 16);
}
__device__ inline float bf2f(unsigned short v) {
    return __uint_as_float((unsigned)v << 16);
}
__device__ inline unsigned cidx(unsigned i) {
    unsigned t = i / CPT;                 // magic-mul div
    return i + t * ROW4 + ROW4;
}
// streaming copy: NT-hinted LOADS (x is read-once, never written -> no coherence hazard);
// REGULAR stores (out is poison-filled by the harness before timing; nt stores left
// stale L2 lines and failed post-timing validation in R14)
__device__ inline void copy_strided(const float* __restrict__ xf, float* __restrict__ of,
                                    unsigned base, unsigned len,
                                    unsigned ct, unsigned nth) {
    const f32x4* __restrict__ x4 = (const f32x4*)xf;
    f32x4* __restrict__ o4 = (f32x4*)of;
    for (unsigned i = ct; i < len; i += nth) {
        unsigned a = cidx(base + i);
        f32x4 v = __builtin_nontemporal_load(x4 + a);
        o4[a] = v;
    }
}

// ---------------- 64x64 MFMA bf16 tile, 4 waves, fragments direct from global ----------------
template<bool ADD_RES, bool BF16_OUT>
__device__ inline void gemm_tile(const unsigned short* __restrict__ A,
                                 const unsigned short* __restrict__ Bt,   // [n][k]
                                 const float* __restrict__ bias,
                                 const float* __restrict__ res,
                                 float* __restrict__ outf, unsigned short* __restrict__ outb,
                                 int by, int bx, size_t orow) {
    int tid  = threadIdx.x;
    int lane = tid & 63, wv = tid >> 6;
    int wr = wv >> 1, wc = wv & 1;
    int l15 = lane & 15, lh = lane >> 4;
    int m0 = by * 64 + wr * 32;
    int n0 = bx * 64 + wc * 32;
    f32x4 acc[2][2] = {};
    const unsigned short* Ar0 = A  + (size_t)(m0 + l15) * CC + lh * 8;
    const unsigned short* Ar1 = Ar0 + 16 * CC;
    const unsigned short* Br0 = Bt + (size_t)(n0 + l15) * CC + lh * 8;
    const unsigned short* Br1 = Br0 + 16 * CC;
    #pragma unroll 4
    for (int k0 = 0; k0 < CC; k0 += 32) {
        short8 a0 = *(const short8*)(Ar0 + k0);
        short8 a1 = *(const short8*)(Ar1 + k0);
        short8 b0 = *(const short8*)(Br0 + k0);
        short8 b1 = *(const short8*)(Br1 + k0);
        acc[0][0] = __builtin_amdgcn_mfma_f32_16x16x32_bf16(a0, b0, acc[0][0], 0, 0, 0);
        acc[0][1] = __builtin_amdgcn_mfma_f32_16x16x32_bf16(a0, b1, acc[0][1], 0, 0, 0);
        acc[1][0] = __builtin_amdgcn_mfma_f32_16x16x32_bf16(a1, b0, acc[1][0], 0, 0, 0);
        acc[1][1] = __builtin_amdgcn_mfma_f32_16x16x32_bf16(a1, b1, acc[1][1], 0, 0, 0);
    }
    #pragma unroll
    for (int mf = 0; mf < 2; ++mf)
        #pragma unroll
        for (int nf = 0; nf < 2; ++nf)
            #pragma unroll
            for (int r = 0; r < 4; ++r) {
                int row = m0 + mf * 16 + lh * 4 + r;
                int col = n0 + nf * 16 + l15;
                float v = acc[mf][nf][r] + bias[col];
                if (ADD_RES) v += res[(size_t)row * CC + col];
                if (BF16_OUT) outb[(size_t)row * orow + col] = f2bf(v);
                else          outf[(size_t)row * orow + col] = v;
            }
}

// ================= K1: CVT (288 x 8 tiles) | LN (512) | ALL 2048 copy =================
__global__ __launch_bounds__(256) void k1(const float* __restrict__ x, const float* __restrict__ w1,
        const float* __restrict__ g, const float* __restrict__ bln,
        const float* __restrict__ Wq, const float* __restrict__ Wk,
        const float* __restrict__ Wv, const float* __restrict__ Wo,
        float* __restrict__ s_shift, unsigned short* __restrict__ tln,
        unsigned short* __restrict__ wt, float* __restrict__ out) {
    __shared__ float smem[32 * 33];
    int bid = blockIdx.x, tid = threadIdx.x;
    if (bid < 288) {
        #pragma unroll
        for (int rep = 0; rep < 8; ++rep) {
            int idx = bid + rep * 288;          // 0..2303
            int mat = idx / 576, tile = idx % 576;
            int tr = tile / 24, tc = tile % 24;
            const float* W = mat == 0 ? Wq : mat == 1 ? Wk : mat == 2 ? Wv : Wo;
            int lr = tid >> 3, lc = (tid & 7) * 4;
            float4 v = *(const float4*)(W + (size_t)(tr * 32 + lr) * CC + tc * 32 + lc);
            smem[lr * 33 + lc + 0] = v.x; smem[lr * 33 + lc + 1] = v.y;
            smem[lr * 33 + lc + 2] = v.z; smem[lr * 33 + lc + 3] = v.w;
            __syncthreads();
            int ln_ = tid >> 3, kc = (tid & 7) * 4;
            us4 o;
            #pragma unroll
            for (int j = 0; j < 4; ++j) o[j] = f2bf(smem[(kc + j) * 33 + ln_]);
            *(us4*)(wt + (size_t)mat * CC * CC + (size_t)(tc * 32 + ln_) * CC + tr * 32 + kc) = o;
            __syncthreads();
        }
    } else if (bid < 288 + NT) {
        int r = bid - 288, seg = r & (NSEG - 1);
        float vals[3]; float local = 0.f;
        #pragma unroll
        for (int i = 0; i < 3; ++i) {
            int c = tid + i * 256;
            float v = x[(size_t)r * PP * CC + c];
            if (seg > 0) v += w1[c] * x[(size_t)(r - 1) * PP * CC + c];
            vals[i] = v; local += v;
        }
        smem[tid] = local; __syncthreads();
        for (int off = 128; off > 0; off >>= 1) {
            if (tid < off) smem[tid] += smem[tid + off];
            __syncthreads();
        }
        float mu = smem[0] * (1.0f / CC); __syncthreads();
        float lv = 0.f;
        #pragma unroll
        for (int i = 0; i < 3; ++i) { float d = vals[i] - mu; lv += d * d; }
        smem[tid] = lv; __syncthreads();
        for (int off = 128; off > 0; off >>= 1) {
            if (tid < off) smem[tid] += smem[tid + off];
            __syncthreads();
        }
        float rstd = rsqrtf(smem[0] * (1.0f / CC) + LN_EPS);
        #pragma unroll
        for (int i = 0; i < 3; ++i) {
            int c = tid + i * 256;
            s_shift[(size_t)r * CC + c] = vals[i];
            tln[(size_t)r * CC + c] = f2bf((vals[i] - mu) * rstd * g[c] + bln[c]);
        }
    }
    copy_strided(x, out, 0u, L1, (unsigned)bid * 256 + tid, 2048u * 256);
}

// ================= K2: QKV GEMM -> bf16 (288) | copy (1760) =================
__global__ __launch_bounds__(256) void k2(const unsigned short* __restrict__ tln,
        const unsigned short* __restrict__ wt,
        const float* __restrict__ bq, const float* __restrict__ bk, const float* __restrict__ bv,
        unsigned short* __restrict__ qkvb,
        const float* __restrict__ x, float* __restrict__ out) {
    int bid = blockIdx.x, tid = threadIdx.x;
    if (bid < 288) {
        int z = bid / 96, rem = bid % 96;
        int by = rem / 12, bx = rem % 12;
        const float* bias = z == 0 ? bq : (z == 1 ? bk : bv);
        gemm_tile<false, true>(tln, wt + (size_t)z * CC * CC, bias, nullptr,
                               nullptr, qkvb + (size_t)z * MN, by, bx, CC);
    } else {
        copy_strided(x, out, B2, L2, (unsigned)(bid - 288) * 256 + tid, 1760u * 256);
    }
}

// ================= K3: attention (384) | copy (1664) =================
__global__ __launch_bounds__(256) void k3(const unsigned short* __restrict__ qkvb,
        unsigned short* __restrict__ ctxb,
        const float* __restrict__ x, float* __restrict__ out) {
    int bid = blockIdx.x, tid = threadIdx.x;
    if (bid < 384) {
        const unsigned short* qb = qkvb;
        const unsigned short* kb = qkvb + MN;
        const unsigned short* vb = qkvb + 2 * MN;
        int bb = bid / NH, h = bid % NH;
        __shared__ float qs[16][HD], ks[16][HD], vs[16][HD];
        __shared__ float sc[16][17];
        __shared__ float rsum[16];
        for (int i = tid; i < 16 * HD; i += 256) {
            int t = i >> 6, d = i & 63;
            size_t gidx = (size_t)(bb * NSEG + t) * CC + h * HD + d;
            qs[t][d] = bf2f(qb[gidx]); ks[t][d] = bf2f(kb[gidx]); vs[t][d] = bf2f(vb[gidx]);
        }
        __syncthreads();
        {
            int t = tid >> 4, s = tid & 15;
            float acc = 0.f;
            #pragma unroll
            for (int d = 0; d < HD; ++d) acc += qs[t][d] * ks[s][d];
            sc[t][s] = acc * 0.125f;
        }
        __syncthreads();
        if (tid < 16) {
            float m = -1e30f;
            #pragma unroll
            for (int s = 0; s < 16; ++s) m = fmaxf(m, sc[tid][s]);
            float sum = 0.f;
            #pragma unroll
            for (int s = 0; s < 16; ++s) { float e = __expf(sc[tid][s] - m); sc[tid][s] = e; sum += e; }
            rsum[tid] = sum;
        }
        __syncthreads();
        for (int i = tid; i < 16 * HD; i += 256) {
            int t = i >> 6, d = i & 63;
            float acc = 0.f;
            #pragma unroll
            for (int s = 0; s < 16; ++s) acc += sc[t][s] * vs[s][d];
            ctxb[(size_t)(bb * NSEG + t) * CC + h * HD + d] = f2bf(acc / rsum[t]);
        }
    } else {
        copy_strided(x, out, B3, L3, (unsigned)(bid - 384) * 256 + tid, 1664u * 256);
    }
}

// ================= K4: O-proj + residual -> out[p=0] (96) | copy (1952) =================
__global__ __launch_bounds__(256) void k4(const unsigned short* __restrict__ ctxb,
        const unsigned short* __restrict__ wto,
        const float* __restrict__ bo, const float* __restrict__ s_shift,
        float* __restrict__ out, const float* __restrict__ x) {
    int bid = blockIdx.x, tid = threadIdx.x;
    if (bid < 96) {
        int by = bid / 12, bx = bid % 12;
        gemm_tile<true, false>(ctxb, wto, bo, s_shift, out, nullptr, by, bx, (size_t)PP * CC);
    } else {
        copy_strided(x, out, B4, L4, (unsigned)(bid - 96) * 256 + tid, 1952u * 256);
    }
}

extern "C" void kernel_launch(void* const* d_in, const int* in_sizes, int n_in,
                              void* d_out, int out_size, void* d_ws, size_t ws_size,
                              hipStream_t stream) {
    const float* x    = (const float*)d_in[0];
    const float* w1   = (const float*)d_in[1];
    const float* ln_g = (const float*)d_in[2];
    const float* ln_b = (const float*)d_in[3];
    const float* Wq   = (const float*)d_in[4];
    const float* bq   = (const float*)d_in[5];
    const float* Wk   = (const float*)d_in[6];
    const float* bk   = (const float*)d_in[7];
    const float* Wv   = (const float*)d_in[8];
    const float* bv   = (const float*)d_in[9];
    const float* Wo   = (const float*)d_in[10];
    const float* bo   = (const float*)d_in[11];
    float* out = (float*)d_out;

    float* s_shift = (float*)d_ws;                            // MN f32
    unsigned short* tln  = (unsigned short*)(s_shift + MN);   // MN bf16
    unsigned short* qkvb = tln + MN;                          // 3*MN bf16
    unsigned short* ctxb = qkvb + 3 * (size_t)MN;             // MN bf16
    unsigned short* wt   = ctxb + MN;                         // 4*CC*CC bf16

    k1<<<2048, 256, 0, stream>>>(x, w1, ln_g, ln_b, Wq, Wk, Wv, Wo, s_shift, tln, wt, out);
    k2<<<2048, 256, 0, stream>>>(tln, wt, bq, bk, bv, qkvb, x, out);
    k3<<<2048, 256, 0, stream>>>(qkvb, ctxb, x, out);
    k4<<<2048, 256, 0, stream>>>(ctxb, wt + (size_t)3 * CC * CC, bo, s_shift, out, x);
}